// Round 1
// baseline (170.435 us; speedup 1.0000x reference)
//
#include <hip/hip_runtime.h>
#include <math.h>

#define NBATCH 4
#define NPTS   8192
#define TPB    256
#define TILES  (NPTS / TPB)        // 32 query tiles per (dir, batch)
#define NBLK   (2 * NBATCH * TILES) // 256 blocks

// Each block: one direction (d1 or d2), one batch, one tile of 256 query
// points. Stages the entire opposite point set (8192 x float4 = 128 KiB)
// into LDS as (x, y, z, norm). Every thread scans all 8192 staged points;
// all lanes read the same LDS address per step -> broadcast, conflict-free.
__global__ __launch_bounds__(TPB, 1) void chamfer_main(
    const float* __restrict__ xyz1,
    const float* __restrict__ xyz2,
    const float* __restrict__ thp,
    double* __restrict__ partial)
{
    __shared__ float4 pts[NPTS];       // 128 KiB (gfx950: 160 KiB/CU)
    __shared__ double wsum[TPB / 64];

    const int bid  = blockIdx.x;
    const int tile = bid & (TILES - 1);
    const int rest = bid / TILES;
    const int b    = rest & (NBATCH - 1);
    const int dir  = rest >> 2;        // 0: d1 (q=xyz1, r=xyz2); 1: d2

    const float* q = (dir == 0 ? xyz1 : xyz2) + (size_t)b * NPTS * 3;
    const float* r = (dir == 0 ? xyz2 : xyz1) + (size_t)b * NPTS * 3;

    // Cooperative staging: 3 contiguous dwords per point; union of lane
    // accesses is contiguous -> coalesced enough for 96 KB of L2-hot data.
    for (int i = threadIdx.x; i < NPTS; i += TPB) {
        float x = r[3 * i + 0], y = r[3 * i + 1], z = r[3 * i + 2];
        pts[i] = make_float4(x, y, z, x * x + y * y + z * z);
    }
    __syncthreads();

    const int qi = tile * TPB + threadIdx.x;
    const float qx = q[3 * qi + 0], qy = q[3 * qi + 1], qz = q[3 * qi + 2];
    const float qn = qx * qx + qy * qy + qz * qz;

    // 4 independent min chains for ILP (occupancy is 1 wave/SIMD).
    float m0 = INFINITY, m1 = INFINITY, m2 = INFINITY, m3 = INFINITY;
    #pragma unroll 2
    for (int j = 0; j < NPTS; j += 4) {
        float4 p0 = pts[j + 0];
        float4 p1 = pts[j + 1];
        float4 p2 = pts[j + 2];
        float4 p3 = pts[j + 3];
        float d0 = (qn + p0.w) - 2.0f * (qx * p0.x + qy * p0.y + qz * p0.z);
        float d1 = (qn + p1.w) - 2.0f * (qx * p1.x + qy * p1.y + qz * p1.z);
        float d2 = (qn + p2.w) - 2.0f * (qx * p2.x + qy * p2.y + qz * p2.z);
        float d3 = (qn + p3.w) - 2.0f * (qx * p3.x + qy * p3.y + qz * p3.z);
        m0 = fminf(m0, d0);
        m1 = fminf(m1, d1);
        m2 = fminf(m2, d2);
        m3 = fminf(m3, d3);
    }
    float dmin = fminf(fminf(m0, m1), fminf(m2, m3));

    const float th = *thp;
    double val = (dmin <= th) ? 0.0 : (double)dmin;

    // Wave(64) shuffle reduce in double, then cross-wave via LDS.
    for (int off = 32; off > 0; off >>= 1)
        val += __shfl_down(val, off, 64);
    const int lane = threadIdx.x & 63;
    const int wid  = threadIdx.x >> 6;
    if (lane == 0) wsum[wid] = val;
    __syncthreads();
    if (threadIdx.x == 0) {
        double s = 0.0;
        #pragma unroll
        for (int w = 0; w < TPB / 64; ++w) s += wsum[w];
        partial[bid] = s;   // deterministic: no atomics
    }
}

__global__ void chamfer_finalize(const double* __restrict__ partial,
                                 float* __restrict__ out)
{
    const int b = threadIdx.x;
    if (b < NBATCH) {
        double s = 0.0;
        for (int dir = 0; dir < 2; ++dir)
            for (int t = 0; t < TILES; ++t)
                s += partial[(dir * NBATCH + b) * TILES + t];
        out[b] = (float)(s / (double)NPTS);   // mean(d1) + mean(d2), N == M
    }
}

extern "C" void kernel_launch(void* const* d_in, const int* in_sizes, int n_in,
                              void* d_out, int out_size, void* d_ws, size_t ws_size,
                              hipStream_t stream) {
    const float* xyz1 = (const float*)d_in[0];
    const float* xyz2 = (const float*)d_in[1];
    const float* thp  = (const float*)d_in[2];
    float* out        = (float*)d_out;
    double* partial   = (double*)d_ws;   // needs NBLK * 8 = 2 KiB of scratch

    chamfer_main<<<NBLK, TPB, 0, stream>>>(xyz1, xyz2, thp, partial);
    chamfer_finalize<<<1, 64, 0, stream>>>(partial, out);
}

// Round 2
// 49.243 us; speedup vs baseline: 3.4611x; 3.4611x over previous
//
#include <hip/hip_runtime.h>
#include <math.h>

#define NBATCH 4
#define NPTS   8192
#define TPB    1024
#define QPB    256                   // queries per block
#define QPT    4                     // queries per lane (register-blocked)
#define NSLICE (TPB / 64)            // 16 slices: one per wave
#define SLICEPTS (NPTS / NSLICE)     // 512 points per slice
#define TILES  (NPTS / QPB)          // 32 query tiles per (dir, batch)
#define NBLK   (2 * NBATCH * TILES)  // 256 blocks = 1 per CU

// Block = (dir, batch, tile of 256 queries). Full opposite point set staged
// in LDS as (-2x, -2y, -2z, ||p||^2) so the inner loop is 3 fma + 1 min per
// (query, point). Wave w scans slice [512w, 512w+512); all 64 lanes read the
// SAME LDS address per step (broadcast, conflict-free). Each lane holds 4
// queries in registers -> 16 VALU ops per LDS read. qn is added after the
// min (min(qn+d') = qn+min d').
__global__ __launch_bounds__(TPB, 4) void chamfer_main(
    const float* __restrict__ xyz1,
    const float* __restrict__ xyz2,
    const float* __restrict__ thp,
    double* __restrict__ partial)
{
    __shared__ float4 pts[NPTS];            // 128 KiB
    __shared__ float  part[NSLICE][QPB];    // 16 KiB: per-slice partial mins
    __shared__ double wsum[NSLICE];

    const int bid  = blockIdx.x;
    const int tile = bid & (TILES - 1);
    const int rest = bid / TILES;
    const int b    = rest & (NBATCH - 1);
    const int dir  = rest >> 2;             // 0: d1 (q=xyz1,r=xyz2); 1: d2

    const float* q = (dir == 0 ? xyz1 : xyz2) + (size_t)b * NPTS * 3;
    const float* r = (dir == 0 ? xyz2 : xyz1) + (size_t)b * NPTS * 3;

    // Stage with -2 premultiply + norm.
    for (int i = threadIdx.x; i < NPTS; i += TPB) {
        float x = r[3 * i + 0], y = r[3 * i + 1], z = r[3 * i + 2];
        pts[i] = make_float4(-2.0f * x, -2.0f * y, -2.0f * z,
                             x * x + y * y + z * z);
    }
    __syncthreads();

    const int lane = threadIdx.x & 63;
    const int w    = threadIdx.x >> 6;      // slice id = wave id
    const int q0   = tile * QPB + lane * QPT;

    float qx[QPT], qy[QPT], qz[QPT], m[QPT];
    #pragma unroll
    for (int k = 0; k < QPT; ++k) {
        qx[k] = q[3 * (q0 + k) + 0];
        qy[k] = q[3 * (q0 + k) + 1];
        qz[k] = q[3 * (q0 + k) + 2];
        m[k]  = INFINITY;
    }

    const float4* sp = &pts[w * SLICEPTS];
    #pragma unroll 1
    for (int j = 0; j < SLICEPTS; j += 4) {
        float4 p0 = sp[j + 0];
        float4 p1 = sp[j + 1];
        float4 p2 = sp[j + 2];
        float4 p3 = sp[j + 3];
        #pragma unroll
        for (int k = 0; k < QPT; ++k) {
            m[k] = fminf(m[k], fmaf(qx[k], p0.x,
                          fmaf(qy[k], p0.y, fmaf(qz[k], p0.z, p0.w))));
            m[k] = fminf(m[k], fmaf(qx[k], p1.x,
                          fmaf(qy[k], p1.y, fmaf(qz[k], p1.z, p1.w))));
            m[k] = fminf(m[k], fmaf(qx[k], p2.x,
                          fmaf(qy[k], p2.y, fmaf(qz[k], p2.z, p2.w))));
            m[k] = fminf(m[k], fmaf(qx[k], p3.x,
                          fmaf(qy[k], p3.y, fmaf(qz[k], p3.z, p3.w))));
        }
    }

    #pragma unroll
    for (int k = 0; k < QPT; ++k)
        part[w][lane * QPT + k] = m[k];
    __syncthreads();

    // Combine the 16 slice-mins per query; add qn; threshold.
    double val = 0.0;
    if (threadIdx.x < QPB) {
        const int ql = threadIdx.x;
        float mv = part[0][ql];
        #pragma unroll
        for (int s = 1; s < NSLICE; ++s) mv = fminf(mv, part[s][ql]);
        const int qi = tile * QPB + ql;
        const float Qx = q[3 * qi + 0], Qy = q[3 * qi + 1], Qz = q[3 * qi + 2];
        const float dmin = (Qx * Qx + Qy * Qy + Qz * Qz) + mv;
        const float th = *thp;
        val = (dmin <= th) ? 0.0 : (double)dmin;
    }

    // Block-wide double sum (deterministic).
    for (int off = 32; off > 0; off >>= 1)
        val += __shfl_down(val, off, 64);
    if (lane == 0) wsum[w] = val;
    __syncthreads();
    if (threadIdx.x == 0) {
        double s = 0.0;
        #pragma unroll
        for (int i = 0; i < NSLICE; ++i) s += wsum[i];
        partial[bid] = s;
    }
}

__global__ void chamfer_finalize(const double* __restrict__ partial,
                                 float* __restrict__ out)
{
    const int b = threadIdx.x;
    if (b < NBATCH) {
        double s = 0.0;
        for (int dir = 0; dir < 2; ++dir)
            for (int t = 0; t < TILES; ++t)
                s += partial[(dir * NBATCH + b) * TILES + t];
        out[b] = (float)(s / (double)NPTS);   // mean(d1)+mean(d2), N == M
    }
}

extern "C" void kernel_launch(void* const* d_in, const int* in_sizes, int n_in,
                              void* d_out, int out_size, void* d_ws, size_t ws_size,
                              hipStream_t stream) {
    const float* xyz1 = (const float*)d_in[0];
    const float* xyz2 = (const float*)d_in[1];
    const float* thp  = (const float*)d_in[2];
    float* out        = (float*)d_out;
    double* partial   = (double*)d_ws;   // NBLK * 8 = 2 KiB scratch

    chamfer_main<<<NBLK, TPB, 0, stream>>>(xyz1, xyz2, thp, partial);
    chamfer_finalize<<<1, 64, 0, stream>>>(partial, out);
}

// Round 3
// 48.162 us; speedup vs baseline: 3.5388x; 1.0224x over previous
//
#include <hip/hip_runtime.h>
#include <math.h>

#define NBATCH 4
#define NPTS   8192
#define TPB    1024
#define QPB    256                   // queries per block
#define QPT    4                     // queries per lane
#define NSLICE (TPB / 64)            // 16 slices: one per wave
#define SLICEPTS (NPTS / NSLICE)     // 512 points per slice per wave
#define TILES  (NPTS / QPB)          // 32 query tiles per (dir, batch)
#define NBLK   (2 * NBATCH * TILES)  // 256 blocks = 1 per CU

typedef float v2f __attribute__((ext_vector_type(2)));

__device__ __forceinline__ float min3f(float a, float b, float c) {
    return fminf(fminf(a, b), c);    // fuses to v_min3_f32
}

// Block = (dir, batch, tile of 256 queries). Opposite point set staged in
// LDS **SoA** as (-2x, -2y, -2z, ||p||^2) so ds_read_b128 yields 4 points'
// same component = 2 packed-f32 pairs. Inner math: 3 v_pk_fma_f32 per
// 2 points per query + 1 v_min3_f32 -> 2.0 VALU instr/pair (vs 4.0 scalar).
// Wave w scans slice [512w,512w+512); all lanes read the same LDS address
// (broadcast, conflict-free). qn added after the min.
__global__ __launch_bounds__(TPB, 4) void chamfer_main(
    const float* __restrict__ xyz1,
    const float* __restrict__ xyz2,
    const float* __restrict__ thp,
    double* __restrict__ partial)
{
    __shared__ float sx[NPTS], sy[NPTS], sz[NPTS], sw[NPTS];  // 128 KiB SoA
    __shared__ float part[NSLICE][QPB];                       // 16 KiB
    __shared__ double wsum[NSLICE];

    const int bid  = blockIdx.x;
    const int tile = bid & (TILES - 1);
    const int rest = bid / TILES;
    const int b    = rest & (NBATCH - 1);
    const int dir  = rest >> 2;             // 0: d1 (q=xyz1,r=xyz2); 1: d2

    const float* q = (dir == 0 ? xyz1 : xyz2) + (size_t)b * NPTS * 3;
    const float* r = (dir == 0 ? xyz2 : xyz1) + (size_t)b * NPTS * 3;

    for (int i = threadIdx.x; i < NPTS; i += TPB) {
        float x = r[3 * i + 0], y = r[3 * i + 1], z = r[3 * i + 2];
        sx[i] = -2.0f * x;
        sy[i] = -2.0f * y;
        sz[i] = -2.0f * z;
        sw[i] = x * x + y * y + z * z;
    }
    __syncthreads();

    const int lane = threadIdx.x & 63;
    const int w    = threadIdx.x >> 6;
    const int q0   = tile * QPB + lane * QPT;

    float qx[QPT], qy[QPT], qz[QPT], m[QPT];
    #pragma unroll
    for (int k = 0; k < QPT; ++k) {
        qx[k] = q[3 * (q0 + k) + 0];
        qy[k] = q[3 * (q0 + k) + 1];
        qz[k] = q[3 * (q0 + k) + 2];
        m[k]  = INFINITY;
    }

    const int base = w * SLICEPTS;
    #pragma unroll 1
    for (int j = 0; j < SLICEPTS; j += 8) {
        // 8 points: 2x ds_read_b128 per component -> 4 packed pairs each.
        float4 X0 = *(const float4*)&sx[base + j];
        float4 X1 = *(const float4*)&sx[base + j + 4];
        float4 Y0 = *(const float4*)&sy[base + j];
        float4 Y1 = *(const float4*)&sy[base + j + 4];
        float4 Z0 = *(const float4*)&sz[base + j];
        float4 Z1 = *(const float4*)&sz[base + j + 4];
        float4 W0 = *(const float4*)&sw[base + j];
        float4 W1 = *(const float4*)&sw[base + j + 4];

        v2f xp[4] = { {X0.x, X0.y}, {X0.z, X0.w}, {X1.x, X1.y}, {X1.z, X1.w} };
        v2f yp[4] = { {Y0.x, Y0.y}, {Y0.z, Y0.w}, {Y1.x, Y1.y}, {Y1.z, Y1.w} };
        v2f zp[4] = { {Z0.x, Z0.y}, {Z0.z, Z0.w}, {Z1.x, Z1.y}, {Z1.z, Z1.w} };
        v2f wp[4] = { {W0.x, W0.y}, {W0.z, W0.w}, {W1.x, W1.y}, {W1.z, W1.w} };

        #pragma unroll
        for (int k = 0; k < QPT; ++k) {
            v2f qxv = { qx[k], qx[k] };
            v2f qyv = { qy[k], qy[k] };
            v2f qzv = { qz[k], qz[k] };
            #pragma unroll
            for (int g = 0; g < 4; ++g) {
                v2f d = __builtin_elementwise_fma(qxv, xp[g],
                        __builtin_elementwise_fma(qyv, yp[g],
                        __builtin_elementwise_fma(qzv, zp[g], wp[g])));
                m[k] = min3f(m[k], d.x, d.y);
            }
        }
    }

    #pragma unroll
    for (int k = 0; k < QPT; ++k)
        part[w][lane * QPT + k] = m[k];
    __syncthreads();

    // Combine 16 slice-mins per query; add qn; threshold.
    double val = 0.0;
    if (threadIdx.x < QPB) {
        const int ql = threadIdx.x;
        float mv = part[0][ql];
        #pragma unroll
        for (int s = 1; s < NSLICE; ++s) mv = fminf(mv, part[s][ql]);
        const int qi = tile * QPB + ql;
        const float Qx = q[3 * qi + 0], Qy = q[3 * qi + 1], Qz = q[3 * qi + 2];
        const float dmin = (Qx * Qx + Qy * Qy + Qz * Qz) + mv;
        const float th = *thp;
        val = (dmin <= th) ? 0.0 : (double)dmin;
    }

    for (int off = 32; off > 0; off >>= 1)
        val += __shfl_down(val, off, 64);
    if (lane == 0) wsum[w] = val;
    __syncthreads();
    if (threadIdx.x == 0) {
        double s = 0.0;
        #pragma unroll
        for (int i = 0; i < NSLICE; ++i) s += wsum[i];
        partial[bid] = s;
    }
}

__global__ void chamfer_finalize(const double* __restrict__ partial,
                                 float* __restrict__ out)
{
    const int b = threadIdx.x;
    if (b < NBATCH) {
        double s = 0.0;
        for (int dir = 0; dir < 2; ++dir)
            for (int t = 0; t < TILES; ++t)
                s += partial[(dir * NBATCH + b) * TILES + t];
        out[b] = (float)(s / (double)NPTS);   // mean(d1)+mean(d2), N == M
    }
}

extern "C" void kernel_launch(void* const* d_in, const int* in_sizes, int n_in,
                              void* d_out, int out_size, void* d_ws, size_t ws_size,
                              hipStream_t stream) {
    const float* xyz1 = (const float*)d_in[0];
    const float* xyz2 = (const float*)d_in[1];
    const float* thp  = (const float*)d_in[2];
    float* out        = (float*)d_out;
    double* partial   = (double*)d_ws;   // NBLK * 8 = 2 KiB scratch

    chamfer_main<<<NBLK, TPB, 0, stream>>>(xyz1, xyz2, thp, partial);
    chamfer_finalize<<<1, 64, 0, stream>>>(partial, out);
}